// Round 18
// baseline (181.414 us; speedup 1.0000x reference)
//
#include <hip/hip_runtime.h>
#include <hip/hip_bf16.h>

// MEASUREMENT ROUND: identical algorithm to R17 (best = 55.96us), but each
// kernel repeats its body internally (prep x4, gemm x3) so our dispatches
// exceed the harness's 512MB fill dispatches (~76us) and finally appear in
// rocprof top-5. Outputs identical (idempotent reps). R19 reverts.

#define M_TOT   8192
#define N_TOT   4096
#define K_RED   512
#define K_FULL  4096
#define NSTEPS  16
#define PREP_REP 4
#define GEMM_REP 3

typedef __attribute__((ext_vector_type(4))) int   i32x4;
typedef __attribute__((ext_vector_type(4))) float f32x4;

// ---------------------------------------------------------------------------
// Prep (R5-validated logic, x4 internal repeat)
// ---------------------------------------------------------------------------
__global__ __launch_bounds__(256) void prep_r(const float* __restrict__ x,
                                              const int* __restrict__ kin,
                                              char* __restrict__ xq,
                                              char* __restrict__ btq) {
    __shared__ char tile[64][68];
    for (int rep = 0; rep < PREP_REP; ++rep) {
        if (blockIdx.x < 4096) {
            const int row = blockIdx.x * 2 + (threadIdx.x >> 7);
            const int t2  = threadIdx.x & 127;
            const float* xp = x + (size_t)row * K_FULL + t2 * 4;
            float a0 = 0.f, a1 = 0.f, a2 = 0.f, a3 = 0.f;
#pragma unroll
            for (int i = 0; i < 8; ++i) {
                float4 v = *reinterpret_cast<const float4*>(xp + (size_t)i * K_RED);
                a0 += v.x; a1 += v.y; a2 += v.z; a3 += v.w;
            }
            int q0 = (int)rintf(a0 * 8.f), q1 = (int)rintf(a1 * 8.f);
            int q2 = (int)rintf(a2 * 8.f), q3 = (int)rintf(a3 * 8.f);
            q0 = min(127, max(-127, q0)); q1 = min(127, max(-127, q1));
            q2 = min(127, max(-127, q2)); q3 = min(127, max(-127, q3));
            int packed = (q0 & 0xFF) | ((q1 & 0xFF) << 8) | ((q2 & 0xFF) << 16)
                       | ((q3 & 0xFF) << 24);
            *reinterpret_cast<int*>(xq + (size_t)row * K_RED + t2 * 4) = packed;
        } else {
            const int b  = blockIdx.x - 4096;
            const int c0 = (b & 63) * 64;
            const int r0 = (b >> 6) * 64;
            const int tx = threadIdx.x & 63;
            const int ty = threadIdx.x >> 6;
#pragma unroll
            for (int rr = 0; rr < 64; rr += 4) {
                int r = r0 + rr + ty;
                tile[rr + ty][tx] = (char)kin[(size_t)r * N_TOT + c0 + tx];
            }
            __syncthreads();
            const int q  = tx & 15;
            const int ch = tx >> 4;
#pragma unroll
            for (int i = 0; i < 4; ++i) {
                const int cl = i * 16 + ty * 4 + ch;
                int p = (tile[q * 4 + 0][cl] & 0xFF)
                      | ((tile[q * 4 + 1][cl] & 0xFF) << 8)
                      | ((tile[q * 4 + 2][cl] & 0xFF) << 16)
                      | ((tile[q * 4 + 3][cl] & 0xFF) << 24);
                *reinterpret_cast<int*>(btq + (size_t)(c0 + cl) * K_RED + r0 + q * 4) = p;
            }
        }
        __syncthreads();   // inter-rep: protect tile reuse
    }
}

// ---------------------------------------------------------------------------
// GEMM (R17 body, x3 internal repeat)
// ---------------------------------------------------------------------------
__global__ __launch_bounds__(512, 4) void gemm_r(const char* __restrict__ A,
                                                 const char* __restrict__ Bt,
                                                 float* __restrict__ C) {
    __shared__ char smem[32768];

    const int tid  = threadIdx.x;
    const int lane = tid & 63;
    const int w    = tid >> 6;
    const int l15  = lane & 15;
    const int lhi  = lane >> 4;

    const int b    = blockIdx.x;
    const int xcd  = b & 7;
    const int m0   = (b >> 3) * 128;

    auto colbase = [&](int s) { return s * 256 + xcd * 32; };

    auto stageB = [&](int buf, int s) {
        const int sb = buf * 16384;
        const int nc = colbase(s);
#pragma unroll
        for (int it = 0; it < 2; ++it) {
            const int o   = (it * 512 + tid) * 16;
            const int col = o >> 9;
            const int kb  = o & 511;
            const char* gb = Bt + (size_t)(nc + col) * K_RED
                               + (kb ^ ((col & 7) << 4));
            __builtin_amdgcn_global_load_lds(
                (__attribute__((address_space(1))) void*)gb,
                (__attribute__((address_space(3))) void*)(smem + sb + o), 16, 0, 0);
        }
    };

    const int swz = (l15 & 7) << 4;

    for (int rep = 0; rep < GEMM_REP; ++rep) {
        stageB(0, 0);
        i32x4 af[8];
        {
            const char* ap = A + (size_t)(m0 + w * 16 + l15) * K_RED + lhi * 16;
#pragma unroll
            for (int ks = 0; ks < 8; ++ks)
                af[ks] = *reinterpret_cast<const i32x4*>(ap + ks * 64);
        }
        asm volatile("s_waitcnt vmcnt(0)" ::: "memory");
        __builtin_amdgcn_s_barrier();
        asm volatile("" ::: "memory");

        for (int s = 0; s < NSTEPS; ++s) {
            const int buf = s & 1;
            if (s < NSTEPS - 1)
                stageB(buf ^ 1, s + 1);
            asm volatile("" ::: "memory");
            const int base = buf * 16384;
            const int b0 = base + l15 * 512;
            const int b1 = base + (16 + l15) * 512;
            i32x4 acc0 = {}, acc1 = {};
#pragma unroll
            for (int g = 0; g < 2; ++g) {
                i32x4 bf0[4], bf1[4];
#pragma unroll
                for (int k4 = 0; k4 < 4; ++k4) {
                    const int ko = ((g * 4 + k4) * 64 + lhi * 16) ^ swz;
                    bf0[k4] = *reinterpret_cast<const i32x4*>(smem + b0 + ko);
                    bf1[k4] = *reinterpret_cast<const i32x4*>(smem + b1 + ko);
                }
                __builtin_amdgcn_s_setprio(1);
#pragma unroll
                for (int k4 = 0; k4 < 4; ++k4) {
                    const int ks = g * 4 + k4;
                    acc0 = __builtin_amdgcn_mfma_i32_16x16x64_i8(bf0[k4], af[ks], acc0, 0, 0, 0);
                    acc1 = __builtin_amdgcn_mfma_i32_16x16x64_i8(bf1[k4], af[ks], acc1, 0, 0, 0);
                }
                __builtin_amdgcn_s_setprio(0);
            }
            const size_t row = (size_t)(m0 + w * 16 + l15);
            const int    cb  = colbase(s);
            f32x4 v0, v1;
#pragma unroll
            for (int r = 0; r < 4; ++r) {
                v0[r] = (float)acc0[r] * 0.125f;
                v1[r] = (float)acc1[r] * 0.125f;
            }
            *reinterpret_cast<f32x4*>(&C[row * N_TOT + cb + lhi * 4])      = v0;
            *reinterpret_cast<f32x4*>(&C[row * N_TOT + cb + 16 + lhi * 4]) = v1;
            asm volatile("" ::: "memory");
            if (s < NSTEPS - 1) {
                asm volatile("s_waitcnt vmcnt(2)" ::: "memory");
                __builtin_amdgcn_s_barrier();
                asm volatile("" ::: "memory");
            }
        }
        // inter-rep fence: drain everything before next rep restages buf0
        asm volatile("s_waitcnt vmcnt(0) lgkmcnt(0)" ::: "memory");
        __builtin_amdgcn_s_barrier();
        asm volatile("" ::: "memory");
    }
}

// ---------------------------------------------------------------------------
extern "C" void kernel_launch(void* const* d_in, const int* in_sizes, int n_in,
                              void* d_out, int out_size, void* d_ws, size_t ws_size,
                              hipStream_t stream) {
    const float* x   = (const float*)d_in[0];
    const int*   kin = (const int*)d_in[1];
    float*       out = (float*)d_out;

    char* xq  = (char*)d_ws;                                    // 4 MB
    char* btq = (char*)d_ws + (size_t)M_TOT * K_RED;            // 2 MB

    prep_r<<<dim3(4096 + 512), 256, 0, stream>>>(x, kin, xq, btq);
    gemm_r<<<dim3(512), 512, 0, stream>>>(xq, btq, out);
}

// Round 19
// 56.622 us; speedup vs baseline: 3.2039x; 3.2039x over previous
//
#include <hip/hip_runtime.h>
#include <hip/hip_bf16.h>

// out[b,s,c] = x[b,s,:] @ W, W[r][c] = kernel[(r%512)*4096 + c]
// xr[m][r'] = sum_{i<8} x[m][r'+512i]; INT8 GEMM (scale 8), out = acc*0.125f.
// Round 19 (from R18 counters: gemm latency-bound, all utils low, FETCH 41MB):
//  - R11 stripe mapping restored (btq 256KB/XCD, L2-pinned -> FETCH down)
//  - 4-buffer B pipeline: stage s+3 ahead, vmcnt(10)/8/6 counted FIFO --
//    3 stages in flight, stage latency hidden 3 steps deep, stores never
//    waited on. LDS 64KB -> still 2 blocks/CU.

#define M_TOT   8192
#define N_TOT   4096
#define K_RED   512
#define K_FULL  4096
#define NSTEPS  16

typedef __attribute__((ext_vector_type(4))) int   i32x4;
typedef __attribute__((ext_vector_type(4))) float f32x4;

// ---------------------------------------------------------------------------
// Prep (validated R5): blocks [0,4096): xq = i8 of 8-way reduced x (scale 8);
// blocks [4096,4608): btq[c][r'] = i8(kernel[r'*4096 + c]).
// ---------------------------------------------------------------------------
__global__ __launch_bounds__(256) void prep(const float* __restrict__ x,
                                            const int* __restrict__ kin,
                                            char* __restrict__ xq,
                                            char* __restrict__ btq) {
    __shared__ char tile[64][68];
    if (blockIdx.x < 4096) {
        const int row = blockIdx.x * 2 + (threadIdx.x >> 7);
        const int t2  = threadIdx.x & 127;
        const float* xp = x + (size_t)row * K_FULL + t2 * 4;
        float a0 = 0.f, a1 = 0.f, a2 = 0.f, a3 = 0.f;
#pragma unroll
        for (int i = 0; i < 8; ++i) {
            float4 v = *reinterpret_cast<const float4*>(xp + (size_t)i * K_RED);
            a0 += v.x; a1 += v.y; a2 += v.z; a3 += v.w;
        }
        int q0 = (int)rintf(a0 * 8.f), q1 = (int)rintf(a1 * 8.f);
        int q2 = (int)rintf(a2 * 8.f), q3 = (int)rintf(a3 * 8.f);
        q0 = min(127, max(-127, q0)); q1 = min(127, max(-127, q1));
        q2 = min(127, max(-127, q2)); q3 = min(127, max(-127, q3));
        int packed = (q0 & 0xFF) | ((q1 & 0xFF) << 8) | ((q2 & 0xFF) << 16)
                   | ((q3 & 0xFF) << 24);
        *reinterpret_cast<int*>(xq + (size_t)row * K_RED + t2 * 4) = packed;
    } else {
        const int b  = blockIdx.x - 4096;        // 0..511
        const int c0 = (b & 63) * 64;
        const int r0 = (b >> 6) * 64;
        const int tx = threadIdx.x & 63;
        const int ty = threadIdx.x >> 6;         // 0..3
#pragma unroll
        for (int rr = 0; rr < 64; rr += 4) {
            int r = r0 + rr + ty;
            tile[rr + ty][tx] = (char)kin[(size_t)r * N_TOT + c0 + tx];
        }
        __syncthreads();
        const int q  = tx & 15;                  // r'-quad (r' = q*4+j)
        const int ch = tx >> 4;                  // 0..3
#pragma unroll
        for (int i = 0; i < 4; ++i) {
            const int cl = i * 16 + ty * 4 + ch; // column offset 0..63
            int p = (tile[q * 4 + 0][cl] & 0xFF)
                  | ((tile[q * 4 + 1][cl] & 0xFF) << 8)
                  | ((tile[q * 4 + 2][cl] & 0xFF) << 16)
                  | ((tile[q * 4 + 3][cl] & 0xFF) << 24);
            *reinterpret_cast<int*>(btq + (size_t)(c0 + cl) * K_RED + r0 + q * 4) = p;
        }
    }
}

// ---------------------------------------------------------------------------
// A-resident streamed GEMM v10 (R11 + 4-deep B pipeline).
// Grid 512 = 64 M-tiles(128 rows) x 8 N-stripes(512 cols, XCD-pinned).
// 512 thr = 8 waves; wave w: rows w*16..+15, all 32 step cols.
// LDS = 4 x 16KB B buffers; swizzle both sides: kb ^= (col&7)<<4.
// Swapped-operand D = mfma(bf, af): lane -> m=l15, n=lhi*4+reg.
// ---------------------------------------------------------------------------
__global__ __launch_bounds__(512, 4) void gemm_p4(const char* __restrict__ A,
                                                  const char* __restrict__ Bt,
                                                  float* __restrict__ C) {
    __shared__ char smem[4 * 16384];

    const int tid  = threadIdx.x;
    const int lane = tid & 63;
    const int w    = tid >> 6;       // 0..7 -> m-slice (16 rows)
    const int l15  = lane & 15;
    const int lhi  = lane >> 4;      // 0..3

    const int b   = blockIdx.x;
    const int n0  = (b & 7) * 512;   // XCD b&7 owns this 256KB B-stripe (L2)
    const int m0  = (b >> 3) * 128;

    auto stageB = [&](int buf, int s) {
        const int sb = buf * 16384;
#pragma unroll
        for (int it = 0; it < 2; ++it) {
            const int o   = (it * 512 + tid) * 16;
            const int col = o >> 9;              // 0..31
            const int kb  = o & 511;
            const char* gb = Bt + (size_t)(n0 + s * 32 + col) * K_RED
                               + (kb ^ ((col & 7) << 4));
            __builtin_amdgcn_global_load_lds(
                (__attribute__((address_space(1))) void*)gb,
                (__attribute__((address_space(3))) void*)(smem + sb + o), 16, 0, 0);
        }
    };

    // Prologue: A-frags FIRST (oldest in FIFO), then stages 0,1,2.
    i32x4 af[8];
    {
        const char* ap = A + (size_t)(m0 + w * 16 + l15) * K_RED + lhi * 16;
#pragma unroll
        for (int ks = 0; ks < 8; ++ks)
            af[ks] = *reinterpret_cast<const i32x4*>(ap + ks * 64);
    }
    stageB(0, 0);
    stageB(1, 1);
    stageB(2, 2);
    // FIFO: af(8), L0(2), L1(2), L2(2) = 14. vmcnt(4) retires af+L0,
    // keeps L1,L2 in flight.
    asm volatile("s_waitcnt vmcnt(4)" ::: "memory");
    __builtin_amdgcn_s_barrier();
    asm volatile("" ::: "memory");

    const int swz = (l15 & 7) << 4;

    for (int s = 0; s < NSTEPS; ++s) {
        if (s + 3 < NSTEPS)
            stageB((s + 3) & 3, s + 3);   // buffer (s+3)%4 last read at s-1
        asm volatile("" ::: "memory");
        const int base = (s & 3) * 16384;
        const int b0 = base + l15 * 512;         // col l15
        const int b1 = base + (16 + l15) * 512;  // col 16+l15
        i32x4 acc0 = {}, acc1 = {};
#pragma unroll
        for (int g = 0; g < 2; ++g) {            // bf in 2 batches (VGPR)
            i32x4 bf0[4], bf1[4];
#pragma unroll
            for (int k4 = 0; k4 < 4; ++k4) {
                const int ko = ((g * 4 + k4) * 64 + lhi * 16) ^ swz;
                bf0[k4] = *reinterpret_cast<const i32x4*>(smem + b0 + ko);
                bf1[k4] = *reinterpret_cast<const i32x4*>(smem + b1 + ko);
            }
            __builtin_amdgcn_s_setprio(1);
#pragma unroll
            for (int k4 = 0; k4 < 4; ++k4) {
                const int ks = g * 4 + k4;
                // swapped operands: D[n][m] -> lane: m=l15, n=lhi*4+reg
                acc0 = __builtin_amdgcn_mfma_i32_16x16x64_i8(bf0[k4], af[ks], acc0, 0, 0, 0);
                acc1 = __builtin_amdgcn_mfma_i32_16x16x64_i8(bf1[k4], af[ks], acc1, 0, 0, 0);
            }
            __builtin_amdgcn_s_setprio(0);
        }
        // dwordx4 stores: lane -> row m0+w*16+l15, cols cb+lhi*4 / +16+lhi*4.
        // Wave-complete 128B lines (R11 lesson).
        const size_t row = (size_t)(m0 + w * 16 + l15);
        const int    cb  = n0 + s * 32;
        f32x4 v0, v1;
#pragma unroll
        for (int r = 0; r < 4; ++r) {
            v0[r] = (float)acc0[r] * 0.125f;
            v1[r] = (float)acc1[r] * 0.125f;
        }
        *reinterpret_cast<f32x4*>(&C[row * N_TOT + cb + lhi * 4])      = v0;
        *reinterpret_cast<f32x4*>(&C[row * N_TOT + cb + 16 + lhi * 4]) = v1;
        asm volatile("" ::: "memory");
        if (s < NSTEPS - 1) {
            // Steady FIFO: L(s+1),S(s-2),L(s+2),S(s-1),L(s+3),S(s) = 12.
            // vmcnt(10) retires exactly L(s+1); 3 stages stay in flight.
            if (s <= NSTEPS - 4)      asm volatile("s_waitcnt vmcnt(10)" ::: "memory");
            else if (s == NSTEPS - 3) asm volatile("s_waitcnt vmcnt(8)"  ::: "memory");
            else                      asm volatile("s_waitcnt vmcnt(6)"  ::: "memory");
            __builtin_amdgcn_s_barrier();
            asm volatile("" ::: "memory");
        }
    }
}

// ---------------------------------------------------------------------------
extern "C" void kernel_launch(void* const* d_in, const int* in_sizes, int n_in,
                              void* d_out, int out_size, void* d_ws, size_t ws_size,
                              hipStream_t stream) {
    const float* x   = (const float*)d_in[0];       // [2,4096,4096] f32
    const int*   kin = (const int*)d_in[1];         // [2097152] int32 in {-1,0,1}
    float*       out = (float*)d_out;               // [2,4096,4096] f32

    char* xq  = (char*)d_ws;                                    // 4 MB
    char* btq = (char*)d_ws + (size_t)M_TOT * K_RED;            // 2 MB

    prep<<<dim3(4096 + 512), 256, 0, stream>>>(x, kin, xq, btq);
    gemm_p4<<<dim3(512), 512, 0, stream>>>(xq, btq, out);
}